// Round 7
// baseline (125.960 us; speedup 1.0000x reference)
//
#include <hip/hip_runtime.h>

#define BB    4
#define CINT  64
#define HH    128
#define WW    128
#define COUT  64
#define DGN   8
#define CG    8
#define KKN   9
#define HO    128
#define WO    128
#define HOWO  16384
#define HWSZ  (HH * WW)
#define NKT   18           // 32-K chunks: K = 576 = 18*32

typedef __bf16 bf16x8 __attribute__((ext_vector_type(8)));
typedef float  f32x4  __attribute__((ext_vector_type(4)));

static __device__ __forceinline__ ushort f2bf(float f) {
    unsigned u = __builtin_bit_cast(unsigned, f);
    u += 0x7fffu + ((u >> 16) & 1u);      // round-to-nearest-even
    return (ushort)(u >> 16);
}
static __device__ __forceinline__ float bf2f(ushort u) {
    return __builtin_bit_cast(float, (unsigned)u << 16);
}

// ---- prep 1: weights into MFMA A-fragment order, bf16 (RNE).
// [kt(18)][mtile(4)][lane(64)] x 8 bf16. A[m=lane&15][k=(lane>>4)*8+j],
// o = mtile*16+m, global K = kt*32 + (lane>>4)*8 + j, K order k=(g*9+kk)*8+c.
__global__ void prep_w(const float* __restrict__ wgt, uint4* __restrict__ wout) {
    int i = blockIdx.x * 256 + threadIdx.x;     // 0..4607
    if (i >= NKT * 4 * 64) return;
    int lane = i & 63;
    int mt   = (i >> 6) & 3;
    int kt   = i >> 8;
    int m = lane & 15, quad = lane >> 4;
    int o = mt * 16 + m;
    union { ushort u[8]; uint4 v; } pk;
#pragma unroll
    for (int j = 0; j < 8; ++j) {
        int k   = kt * 32 + quad * 8 + j;
        int gkk = k >> 3, c = k & 7;
        int g   = gkk / 9, kk = gkk - 9 * g;
        pk.u[j] = f2bf(wgt[(o * CINT + g * CG + c) * KKN + kk]);
    }
    wout[i] = pk.v;
}

// ---- prep 2: x [B, DG*CG, H, W] f32 -> xh [B, DG, H, W, CG] bf16 (16B granules, RNE)
__global__ void prep_x(const float* __restrict__ x, uint4* __restrict__ xh) {
    int i  = blockIdx.x * 256 + threadIdx.x;    // over B*DG*H*W = 524288
    int yx = i & (HWSZ - 1);
    int bg = i >> 14;
    const float* xp = x + (size_t)bg * CG * HWSZ + yx;
    union { ushort u[8]; uint4 v; } pk;
#pragma unroll
    for (int c = 0; c < CG; ++c) pk.u[c] = f2bf(xp[c * HWSZ]);
    xh[i] = pk.v;
}

// ---- main: NO LDS, NO barriers. Wave = 32 pixels x 64 outs.
// Lane (n,quad): produces B-frags for pixels {base+n, base+16+n} at
// gkk = kt*4+quad; 4 A-frags (m-tiles) are reused for both -> weight
// traffic per pixel halves vs R6 (302->151 MB L2 traffic; R3-R6 showed
// time tracks total VMEM work, not occupancy/barriers).
__global__ __launch_bounds__(256, 3) void dcn_mfma(
    const uint4* __restrict__ xh, const float* __restrict__ off,
    const uint4* __restrict__ wq, const float* __restrict__ bias,
    float* __restrict__ out)
{
    const int tid  = threadIdx.x;
    const int wave = tid >> 6;
    const int lane = tid & 63;
    const int n    = lane & 15;
    const int quad = lane >> 4;

    const int bid  = blockIdx.x;                       // 0..511
    const int tile = ((bid & 7) << 6) | (bid >> 3);    // XCD-contiguous spans
    const int pix_blk  = tile * 128;                   // block's 128-px base
    const int b        = pix_blk >> 14;
    const int rem_blk  = pix_blk & 16383;              // multiple of 128 -> one row
    const int ho       = rem_blk >> 7;                 // shared by whole block
    const int wo0      = wave * 32 + n;                // lane's first pixel col
    const int rem0     = rem_blk + wo0;
    const float fy0 = (float)(ho - 1);
    const float fx0 = (float)(wo0 - 1);

    f32x4 acc[4][2];
#pragma unroll
    for (int mt = 0; mt < 4; ++mt) {
        acc[mt][0] = (f32x4){0.f, 0.f, 0.f, 0.f};
        acc[mt][1] = (f32x4){0.f, 0.f, 0.f, 0.f};
    }

    const uint4* xb = xh + (size_t)b * DGN * HWSZ;

#pragma unroll
    for (int kt = 0; kt < NKT; ++kt) {
        // A-frags for this kt (coalesced dwordx4, L2-hot; reused for 32 px)
        uint4 aw0 = wq[(kt * 4 + 0) * 64 + lane];
        uint4 aw1 = wq[(kt * 4 + 1) * 64 + lane];
        uint4 aw2 = wq[(kt * 4 + 2) * 64 + lane];
        uint4 aw3 = wq[(kt * 4 + 3) * 64 + lane];

        const int gkk = kt * 4 + quad;              // 0..71
        const int g = gkk / 9, kk = gkk - 9 * g;
        const float kdy = (float)(kk / 3);
        const float kdx = (float)(kk - (kk / 3) * 3);
        const float* offb = off + ((size_t)((b * DGN + g) * KKN + kk) * 2) * HOWO + rem0;
        const uint4* xgp = xb + (size_t)g * HWSZ;

        bf16x8 bfrag[2];
#pragma unroll
        for (int h = 0; h < 2; ++h) {
            float dy = offb[h * 16];
            float dx = offb[HOWO + h * 16];
            float py  = fy0 + kdy + dy;
            float pxx = fx0 + (float)(h * 16) + kdx + dx;
            float y0f = floorf(py), x0f = floorf(pxx);
            int y0 = (int)y0f, x0 = (int)x0f;
            float ly = py - y0f, lx = pxx - x0f;
            float hy = 1.f - ly, hx = 1.f - lx;
            float w00 = hy * hx, w01 = hy * lx, w10 = ly * hx, w11 = ly * lx;
            int y1 = y0 + 1, x1 = x0 + 1;
            bool vy0 = (unsigned)y0 < (unsigned)HH, vy1 = (unsigned)y1 < (unsigned)HH;
            bool vx0 = (unsigned)x0 < (unsigned)WW, vx1 = (unsigned)x1 < (unsigned)WW;
            if (!(vy0 && vx0)) w00 = 0.f;
            if (!(vy0 && vx1)) w01 = 0.f;
            if (!(vy1 && vx0)) w10 = 0.f;
            if (!(vy1 && vx1)) w11 = 0.f;
            int y0c = min(max(y0, 0), HH - 1), y1c = min(max(y1, 0), HH - 1);
            int x0c = min(max(x0, 0), WW - 1), x1c = min(max(x1, 0), WW - 1);
            uint4 q00 = xgp[y0c * WW + x0c];
            uint4 q01 = xgp[y0c * WW + x1c];
            uint4 q10 = xgp[y1c * WW + x0c];
            uint4 q11 = xgp[y1c * WW + x1c];
            const ushort* u00 = (const ushort*)&q00;
            const ushort* u01 = (const ushort*)&q01;
            const ushort* u10 = (const ushort*)&q10;
            const ushort* u11 = (const ushort*)&q11;
            union { unsigned w[4]; bf16x8 v; } pk;
#pragma unroll
            for (int j = 0; j < 4; ++j) {
                float v0 = w00 * bf2f(u00[2*j])   + w01 * bf2f(u01[2*j])
                         + w10 * bf2f(u10[2*j])   + w11 * bf2f(u11[2*j]);
                float v1 = w00 * bf2f(u00[2*j+1]) + w01 * bf2f(u01[2*j+1])
                         + w10 * bf2f(u10[2*j+1]) + w11 * bf2f(u11[2*j+1]);
                // truncating pack (v_perm pattern): hi16(v1) | hi16(v0)
                pk.w[j] = (__builtin_bit_cast(unsigned, v1) & 0xffff0000u)
                        | (__builtin_bit_cast(unsigned, v0) >> 16);
            }
            bfrag[h] = pk.v;
        }

#pragma unroll
        for (int h = 0; h < 2; ++h) {
            acc[0][h] = __builtin_amdgcn_mfma_f32_16x16x32_bf16(
                            __builtin_bit_cast(bf16x8, aw0), bfrag[h], acc[0][h], 0, 0, 0);
            acc[1][h] = __builtin_amdgcn_mfma_f32_16x16x32_bf16(
                            __builtin_bit_cast(bf16x8, aw1), bfrag[h], acc[1][h], 0, 0, 0);
            acc[2][h] = __builtin_amdgcn_mfma_f32_16x16x32_bf16(
                            __builtin_bit_cast(bf16x8, aw2), bfrag[h], acc[2][h], 0, 0, 0);
            acc[3][h] = __builtin_amdgcn_mfma_f32_16x16x32_bf16(
                            __builtin_bit_cast(bf16x8, aw3), bfrag[h], acc[3][h], 0, 0, 0);
        }
    }

    // C/D layout: col = lane&15 (pixel within 16), row = quad*4 + r
    float* outp = out + (size_t)b * COUT * HOWO + rem_blk + wave * 32 + n;
#pragma unroll
    for (int mt = 0; mt < 4; ++mt) {
        const float4 bq = *(const float4*)&bias[mt * 16 + quad * 4];
#pragma unroll
        for (int r = 0; r < 4; ++r) {
            int o = mt * 16 + quad * 4 + r;
            outp[(size_t)o * HOWO]      = acc[mt][0][r] + ((const float*)&bq)[r];
            outp[(size_t)o * HOWO + 16] = acc[mt][1][r] + ((const float*)&bq)[r];
        }
    }
}

extern "C" void kernel_launch(void* const* d_in, const int* in_sizes, int n_in,
                              void* d_out, int out_size, void* d_ws, size_t ws_size,
                              hipStream_t stream) {
    const float* x    = (const float*)d_in[0];
    const float* off  = (const float*)d_in[1];
    const float* wgt  = (const float*)d_in[2];
    const float* bias = (const float*)d_in[3];
    float* out = (float*)d_out;

    uint4* xh = (uint4*)d_ws;                             // 8,388,608 B
    uint4* wq = (uint4*)((char*)d_ws + 8388608);          // 73,728 B

    prep_x<<<dim3(BB * DGN * HWSZ / 256), dim3(256), 0, stream>>>(x, xh);
    prep_w<<<dim3(NKT), dim3(256), 0, stream>>>(wgt, wq);
    dcn_mfma<<<dim3(BB * HO * WO / 128), dim3(256), 0, stream>>>(xh, off, wq, bias, out);
}